// Round 2
// baseline (218.927 us; speedup 1.0000x reference)
//
#include <hip/hip_runtime.h>
#include <hip/hip_bf16.h>

// CrossModalContrastiveLoss: B=8, C=256, H=W=32 -> N=8192 vectors of dim 256.
// loss = -( P - 1024 * sum_i log(sum_j exp(S_ij)) ) / 8388608,
// S = normalize(rgb) @ normalize(x)^T / 0.1.
// P analytic via bilinearity: positives for row i are cols j%8 == i/1024 ->
// P = ln2 * sum_b <sum_{i in b} A_q,i , sum_{j%8==b} x_q,j>  where A_q carries
// the k2 = 10*log2(e) scale folded in at quantization (so S_mfma = k2*sim and
// exp(10*sim) = exp2(S_mfma) with zero epilogue multiplies).
//
// Round-11: the GEMM is LDS-read-throughput-bound, not schedule-bound.
// Measured: 4.19M conflict cycles / 1.05M ds_read_b64 = +4 cyc each -> 8
// cyc/read; per chunk-period 4 blocks x (128 reads x 8 + stage) ~ 4.6k cyc
// = the measured 4.1k cyc/chunk. Old mapping (wave = 32 rows x ALL 512
// cols) made every wave read the whole 64-col chunk: 64 KB LDS reads per
// 16 KB staged. New mapping: 2x2 wave grid, wave = 64 rows x 256-col half
// -> each wave reads 32 of the 64 chunk cols -> LDS reads HALVE. A-panel
// 64 rows/wave = 64 VGPRs; acc sliced 16-cols at a time keeps peak ~125
// regs for 4 blocks/CU.

#define HWsz 1024
#define Cdim 256
#define Nvec 8192
#define CHW  (Cdim * HWsz)
#define NBLK 1024   // 16 strips x 64 rowgroups

typedef __attribute__((ext_vector_type(4))) float f32x4;

// 32 vectors per block (all one batch), C split 8 ways. Quantizes to fp8
// e4m3 (rgb side pre-scaled by k2), stores (N,C) row-major, and accumulates
// per-batch channel sums of the dequantized values (for analytic P).
__global__ __launch_bounds__(256) void norm_kernel(
    const float* __restrict__ rgb, const float* __restrict__ x,
    unsigned char* __restrict__ rgbq, unsigned char* __restrict__ xq,
    float* __restrict__ bsums) {
  __shared__ float ssp[8][32];
  __shared__ __align__(16) unsigned char tile[32][272];  // 272 = 16*17
  const int t = threadIdx.x;
  const int nl = t & 31;        // vector within block
  const int part = t >> 5;      // 0..7: channel chunk
  const int isx = blockIdx.y;
  const float* src = isx ? x : rgb;
  unsigned char* dst = isx ? xq : rgbq;
  const int n0 = blockIdx.x * 32;
  const int n = n0 + nl;
  const int b = n >> 10;        // uniform per block
  const int hw = n & 1023;
  const float* p = src + (size_t)b * CHW + (size_t)(part * 32) * HWsz + hw;

  float v[32];
  float ss = 0.f;
#pragma unroll
  for (int j = 0; j < 32; ++j) {
    v[j] = p[(size_t)j * HWsz];
    ss += v[j] * v[j];
  }
  ssp[part][nl] = ss;
  __syncthreads();
  float tot = 0.f;
#pragma unroll
  for (int q = 0; q < 8; ++q) tot += ssp[q][nl];
  const float k2 = 14.4269504089f;  // (1/T) * log2(e), folded into rgb side
  const float inv = (isx ? 1.0f : k2) / fmaxf(sqrtf(tot), 1e-12f);

#pragma unroll
  for (int c0 = 0; c0 < 32; c0 += 4) {
    int pk = 0;
    pk = __builtin_amdgcn_cvt_pk_fp8_f32(v[c0] * inv, v[c0 + 1] * inv, pk, false);
    pk = __builtin_amdgcn_cvt_pk_fp8_f32(v[c0 + 2] * inv, v[c0 + 3] * inv, pk, true);
    *reinterpret_cast<unsigned int*>(&tile[nl][part * 32 + c0]) =
        (unsigned int)pk;
  }
  __syncthreads();

  // coalesced store: 2 passes x (16 rows x 256 B)
#pragma unroll
  for (int pass = 0; pass < 2; ++pass) {
    const int r = pass * 16 + (t >> 4);
    const int ck = (t & 15) * 16;
    *reinterpret_cast<uint4*>(dst + (size_t)(n0 + r) * Cdim + ck) =
        *reinterpret_cast<const uint4*>(&tile[r][ck]);
  }

  // per-channel column sum of DEQUANTIZED values (exactly what MFMA sees)
  float csum = 0.f;
#pragma unroll
  for (int r = 0; r < 32; ++r)
    csum += __builtin_amdgcn_cvt_f32_fp8((unsigned int)tile[r][t], 0);
  atomicAdd(&bsums[(isx ? 2048 : 0) + b * 256 + t], csum);
}

// Block = 4 waves (2 row-bands x 2 col-halves), 128 rows x 512-col strip,
// fp8. A-panel 64 rows/wave in regs (8 s-steps x 4 mi longs = 64 VGPRs).
// B streamed as 8 chunks of 64 cols x 256 K through double-buffered
// 2x16 KB LDS; each wave reads only its 32-col half of each chunk.
//
// fp8 LDS swizzle (16-B staging granule): col's 16 units placed at
//   phys(unit) = ((unit>>1) ^ (col&7) ^ ((unit&1)<<2)) + ((unit&1)<<3)
// Read formula depends on col only via col&7 = l15&7 (col-base is a
// multiple of 8 in both old and new mappings). Inverted on the GLOBAL
// address side so the wave-uniform base + lane*16 constraint of
// global_load_lds is preserved.
__global__ __launch_bounds__(256, 4) void gemm_loss_kernel(
    const unsigned char* __restrict__ A, const unsigned char* __restrict__ Bq,
    float* __restrict__ sumexp, const float* __restrict__ bsums,
    unsigned int* __restrict__ done, float* __restrict__ out) {
  __shared__ __align__(16) unsigned char sB[2][16384];
  __shared__ float part4[4], part4b[4];
  __shared__ unsigned int is_last;

  const int tid  = threadIdx.x;
  const int lane = tid & 63;
  const int w    = tid >> 6;      // wave 0..3 (staging group)
  const int wr   = w >> 1;        // row band: rows wr*64..+64
  const int wc   = w & 1;         // col half: chunk cols wc*32..+32
  const int strip = blockIdx.x;   // 0..15: cols strip*512..+512 (XCD-pinned)
  const int rg   = blockIdx.y;    // 0..63: rows rg*128..+128
  const int quad = lane >> 4;
  const int l15  = lane & 15;

  // ---- A fragments: direct global -> 64 regs/wave, once per block ----
  long areg[8][4];
#pragma unroll
  for (int mi = 0; mi < 4; ++mi) {
    const unsigned char* rp =
        A + (size_t)(rg * 128 + wr * 64 + mi * 16 + l15) * Cdim + quad * 8;
#pragma unroll
    for (int s = 0; s < 8; ++s)
      areg[s][mi] = *reinterpret_cast<const long*>(rp + s * 32);
  }

  // staging lane constants: lane = c4*16 + u writes (col base+c4, slot u)
  const int u_  = l15;
  const int c4  = quad;
  const int gx  = (u_ & 7) ^ ((u_ >> 3) << 2);
  const int godd = u_ >> 3;   // global unit parity this slot holds
  // reader lane constants
  const int sxor = (l15 & 7) ^ ((quad >> 1) << 2);
  const int boff = ((quad >> 1) << 7) + ((quad & 1) << 3);

  float rowexp[16];
#pragma unroll
  for (int i = 0; i < 16; ++i) rowexp[i] = 0.f;

  const unsigned char* Bbase = Bq + (size_t)strip * 512 * Cdim;

  // prefetch chunk 0
#pragma unroll
  for (int i = 0; i < 4; ++i) {
    const int colw = w * 16 + i * 4 + c4;
    const unsigned char* gp = Bbase + (size_t)colw * Cdim +
                              32 * (gx ^ (colw & 7)) + godd * 16;
    unsigned char* lp = &sB[0][(w * 16 + i * 4) * 256];
    __builtin_amdgcn_global_load_lds(
        (const __attribute__((address_space(1))) void*)gp,
        (__attribute__((address_space(3))) void*)lp, 16, 0, 0);
  }
  __syncthreads();

  for (int c = 0; c < 8; ++c) {
    const int bf = c & 1;
    if (c < 7) {  // prefetch next chunk (overlaps this chunk's MFMA)
#pragma unroll
      for (int i = 0; i < 4; ++i) {
        const int colw = w * 16 + i * 4 + c4;
        const unsigned char* gp = Bbase + (size_t)((c + 1) * 64 + colw) * Cdim +
                                  32 * (gx ^ (colw & 7)) + godd * 16;
        unsigned char* lp = &sB[bf ^ 1][(w * 16 + i * 4) * 256];
        __builtin_amdgcn_global_load_lds(
            (const __attribute__((address_space(1))) void*)gp,
            (__attribute__((address_space(3))) void*)lp, 16, 0, 0);
      }
    }

    // wave reads ONLY its 32-col half, in two 16-col slices
#pragma unroll
    for (int sl = 0; sl < 2; ++sl) {
      long bfr[8];
#pragma unroll
      for (int s = 0; s < 8; ++s)
        bfr[s] = *reinterpret_cast<const long*>(
            &sB[bf][(wc * 32 + sl * 16 + l15) * 256 +
                    (((s ^ sxor) << 4) + boff)]);

      f32x4 acc[4];
#pragma unroll
      for (int mi = 0; mi < 4; ++mi) acc[mi] = (f32x4){0.f, 0.f, 0.f, 0.f};

      __builtin_amdgcn_s_setprio(1);
#pragma unroll
      for (int s = 0; s < 8; ++s)
#pragma unroll
        for (int mi = 0; mi < 4; ++mi)
          acc[mi] = __builtin_amdgcn_mfma_f32_16x16x32_fp8_fp8(
              areg[s][mi], bfr[s], acc[mi], 0, 0, 0);
      __builtin_amdgcn_s_setprio(0);

      // rowexp += exp2(S_mfma)  (k2 pre-folded into A)
#pragma unroll
      for (int mi = 0; mi < 4; ++mi)
#pragma unroll
        for (int r = 0; r < 4; ++r)
          rowexp[mi * 4 + r] += __builtin_amdgcn_exp2f(acc[mi][r]);
    }

    __syncthreads();  // buffer reuse; prefetch had full compute to land
  }

  // ---- epilogue: one reduce + atomic per row slot (col-halves merge
  // via atomicAdd: each row gets 16 strips x 2 halves = 32 adds) ----
#pragma unroll
  for (int idx = 0; idx < 16; ++idx) {
    float se = rowexp[idx];
    se += __shfl_xor(se, 1);
    se += __shfl_xor(se, 2);
    se += __shfl_xor(se, 4);
    se += __shfl_xor(se, 8);
    if (l15 == 0) {
      const int row =
          rg * 128 + wr * 64 + (idx >> 2) * 16 + quad * 4 + (idx & 3);
      atomicAdd(&sumexp[row], se);
    }
  }

  // ---- last block finalizes the loss ----
  if (tid == 0) {
    __threadfence();
    is_last = (atomicAdd(done, 1u) == NBLK - 1) ? 1u : 0u;
  }
  __syncthreads();
  if (is_last) {
    __threadfence();  // acquire: all blocks' sumexp atomics visible
    float lsum = 0.f;
    for (int i = tid; i < Nvec; i += 256) lsum += logf(sumexp[i]);
    // analytic positive-sum: P = ln2 * sum_b <rgbsum_b, xsum_b>
    float pp = 0.f;
#pragma unroll
    for (int b = 0; b < 8; ++b)
      pp += bsums[b * 256 + tid] * bsums[2048 + b * 256 + tid];
#pragma unroll
    for (int off = 1; off < 64; off <<= 1) {
      lsum += __shfl_xor(lsum, off);
      pp   += __shfl_xor(pp, off);
    }
    if ((tid & 63) == 0) { part4[w] = lsum; part4b[w] = pp; }
    __syncthreads();
    if (tid == 0) {
      float total_lse = 0.f, P = 0.f;
#pragma unroll
      for (int i = 0; i < 4; ++i) { total_lse += part4[i]; P += part4b[i]; }
      P *= 0.69314718056f;  // ln 2
      out[0] = -(P - 1024.0f * total_lse) / (8388608.0f + 1e-8f);
    }
  }
}

extern "C" void kernel_launch(void* const* d_in, const int* in_sizes, int n_in,
                              void* d_out, int out_size, void* d_ws,
                              size_t ws_size, hipStream_t stream) {
  const float* rgb = (const float*)d_in[0];
  const float* x   = (const float*)d_in[1];
  char* ws = (char*)d_ws;
  unsigned char* rgbq = (unsigned char*)ws;                             // 2 MiB
  unsigned char* xq   = (unsigned char*)(ws + (size_t)2 * 1024 * 1024); // 2 MiB
  float* sumexp = (float*)(ws + (size_t)4 * 1024 * 1024);  // 8192 floats
  float* bsums  = sumexp + Nvec;                           // 2x8x256 floats
  unsigned int* done = (unsigned int*)(bsums + 4096);

  hipMemsetAsync(sumexp, 0, (Nvec + 4096 + 4) * sizeof(float), stream);
  norm_kernel<<<dim3(256, 2), 256, 0, stream>>>(rgb, x, rgbq, xq, bsums);
  gemm_loss_kernel<<<dim3(16, 64), 256, 0, stream>>>(rgbq, xq, sumexp, bsums,
                                                     done, (float*)d_out);
}

// Round 3
// 154.046 us; speedup vs baseline: 1.4212x; 1.4212x over previous
//
#include <hip/hip_runtime.h>
#include <hip/hip_bf16.h>

// CrossModalContrastiveLoss: B=8, C=256, H=W=32 -> N=8192 vectors of dim 256.
// loss = -( P - 1024 * sum_i log(sum_j exp(S_ij)) ) / 8388608,
// S = normalize(rgb) @ normalize(x)^T / 0.1.
// positives for row i are cols j with j%8 == i/1024 (reference uses
// repeat_interleave vs tile indexing). A_q carries k2 = 10*log2(e) folded in
// at quantization, so S_mfma = k2*sim and exp(10*sim) = exp2(S_mfma).
//
// Round-12: (a) revert gemm to the proven round-1 body (round-11's 2x2
// wave tiling needed ~140 VGPRs under a 128 cap -> 214 MB scratch spill).
// (b) Pipe accounting shows gemm has no pipe >25% busy (LDS 13.7us, MFMA
// ~12.6us, VALU ~9.4us of 55us) -> latency-bound; leave structure alone and
// attack the ~60us of NON-gemm time instead: memset dispatch removed (norm
// zeroes sumexp/done/Pacc at its top, stream-ordered before gemm), and the
// whole bsums path is deleted -- P is now accumulated inside the gemm from
// the raw MFMA accs: every lane's cols are ≡ l15 (mod 8), so lane is
// positive iff (l15&7)==batch(rowgroup); sum acc unconditionally, mask
// per-lane at the end, one atomic per wave into Pacc[strip]. ln2*k2 = 1/T
// keeps the epilogue constant identical. norm loses its csum pass.

#define HWsz 1024
#define Cdim 256
#define Nvec 8192
#define CHW  (Cdim * HWsz)
#define NBLK 1024   // 16 strips x 64 rowgroups

typedef __attribute__((ext_vector_type(4))) float f32x4;

// 32 vectors per block (all one batch), C split 8 ways. Quantizes to fp8
// e4m3 (rgb side pre-scaled by k2), stores (N,C) row-major. Also zeroes
// the accumulators the gemm kernel needs (replaces the memset dispatch).
__global__ __launch_bounds__(256) void norm_kernel(
    const float* __restrict__ rgb, const float* __restrict__ x,
    unsigned char* __restrict__ rgbq, unsigned char* __restrict__ xq,
    float* __restrict__ sumexp, float* __restrict__ Pacc,
    unsigned int* __restrict__ done) {
  __shared__ float ssp[8][32];
  __shared__ __align__(16) unsigned char tile[32][272];  // 272 = 16*17
  const int t = threadIdx.x;
  const int nl = t & 31;        // vector within block
  const int part = t >> 5;      // 0..7: channel chunk
  const int isx = blockIdx.y;
  const int bx = blockIdx.x;

  // ---- zero gemm accumulators (this kernel precedes gemm in-stream) ----
  if (t < 16) sumexp[(isx * 256 + bx) * 16 + t] = 0.f;
  if (isx == 0 && bx == 0) {
    if (t >= 32 && t < 48) Pacc[t - 32] = 0.f;
    if (t == 63) *done = 0u;
  }

  const float* src = isx ? x : rgb;
  unsigned char* dst = isx ? xq : rgbq;
  const int n0 = bx * 32;
  const int n = n0 + nl;
  const int b = n >> 10;        // uniform per block
  const int hw = n & 1023;
  const float* p = src + (size_t)b * CHW + (size_t)(part * 32) * HWsz + hw;

  float v[32];
  float ss = 0.f;
#pragma unroll
  for (int j = 0; j < 32; ++j) {
    v[j] = p[(size_t)j * HWsz];
    ss += v[j] * v[j];
  }
  ssp[part][nl] = ss;
  __syncthreads();
  float tot = 0.f;
#pragma unroll
  for (int q = 0; q < 8; ++q) tot += ssp[q][nl];
  const float k2 = 14.4269504089f;  // (1/T) * log2(e), folded into rgb side
  const float inv = (isx ? 1.0f : k2) / fmaxf(sqrtf(tot), 1e-12f);

#pragma unroll
  for (int c0 = 0; c0 < 32; c0 += 4) {
    int pk = 0;
    pk = __builtin_amdgcn_cvt_pk_fp8_f32(v[c0] * inv, v[c0 + 1] * inv, pk, false);
    pk = __builtin_amdgcn_cvt_pk_fp8_f32(v[c0 + 2] * inv, v[c0 + 3] * inv, pk, true);
    *reinterpret_cast<unsigned int*>(&tile[nl][part * 32 + c0]) =
        (unsigned int)pk;
  }
  __syncthreads();

  // coalesced store: 2 passes x (16 rows x 256 B)
#pragma unroll
  for (int pass = 0; pass < 2; ++pass) {
    const int r = pass * 16 + (t >> 4);
    const int ck = (t & 15) * 16;
    *reinterpret_cast<uint4*>(dst + (size_t)(n0 + r) * Cdim + ck) =
        *reinterpret_cast<const uint4*>(&tile[r][ck]);
  }
}

// Block = 4 waves, 128 rows x 512-col strip, fp8. A-panel 32 rows/wave in
// regs (8 s-steps x 2 mi longs = 32 VGPRs). B streamed as 8 chunks of 64
// cols x 256 K through double-buffered 2x16 KB LDS.
//
// fp8 LDS swizzle (16-B staging granule): col's 16 units placed at
//   phys(unit) = ((unit>>1) ^ (col&7) ^ ((unit&1)<<2)) + ((unit&1)<<3)
// Inverted on the GLOBAL address side so the wave-uniform base + lane*16
// constraint of global_load_lds is preserved.
__global__ __launch_bounds__(256, 4) void gemm_loss_kernel(
    const unsigned char* __restrict__ A, const unsigned char* __restrict__ Bq,
    float* __restrict__ sumexp, float* __restrict__ Pacc,
    unsigned int* __restrict__ done, float* __restrict__ out) {
  __shared__ __align__(16) unsigned char sB[2][16384];
  __shared__ float part4[4];
  __shared__ unsigned int is_last;

  const int tid  = threadIdx.x;
  const int lane = tid & 63;
  const int w    = tid >> 6;      // wave 0..3 -> rows w*32..+32
  const int strip = blockIdx.x;   // 0..15: cols strip*512..+512 (XCD-pinned)
  const int rg   = blockIdx.y;    // 0..63: rows rg*128..+128
  const int quad = lane >> 4;
  const int l15  = lane & 15;
  const int bi   = rg >> 3;       // batch of this rowgroup (128 rows/batch-slice)

  // ---- A fragments: direct global -> 32 regs/wave, once per block ----
  long areg[8][2];
#pragma unroll
  for (int mi = 0; mi < 2; ++mi) {
    const unsigned char* rp =
        A + (size_t)(rg * 128 + w * 32 + mi * 16 + l15) * Cdim + quad * 8;
#pragma unroll
    for (int s = 0; s < 8; ++s)
      areg[s][mi] = *reinterpret_cast<const long*>(rp + s * 32);
  }

  // staging lane constants: lane = c4*16 + u writes (col base+c4, slot u)
  const int u_  = l15;
  const int c4  = quad;
  const int gx  = (u_ & 7) ^ ((u_ >> 3) << 2);
  const int godd = u_ >> 3;   // global unit parity this slot holds
  // reader lane constants
  const int sxor = (l15 & 7) ^ ((quad >> 1) << 2);
  const int boff = ((quad >> 1) << 7) + ((quad & 1) << 3);

  float rowexp[8];
#pragma unroll
  for (int i = 0; i < 8; ++i) rowexp[i] = 0.f;
  float pAll = 0.f;   // sum of ALL this lane's acc values (masked at end)

  const unsigned char* Bbase = Bq + (size_t)strip * 512 * Cdim;

  // prefetch chunk 0
#pragma unroll
  for (int i = 0; i < 4; ++i) {
    const int colw = w * 16 + i * 4 + c4;
    const unsigned char* gp = Bbase + (size_t)colw * Cdim +
                              32 * (gx ^ (colw & 7)) + godd * 16;
    unsigned char* lp = &sB[0][(w * 16 + i * 4) * 256];
    __builtin_amdgcn_global_load_lds(
        (const __attribute__((address_space(1))) void*)gp,
        (__attribute__((address_space(3))) void*)lp, 16, 0, 0);
  }
  __syncthreads();

  for (int c = 0; c < 8; ++c) {
    const int bf = c & 1;
    if (c < 7) {  // prefetch next chunk (overlaps this chunk's MFMA)
#pragma unroll
      for (int i = 0; i < 4; ++i) {
        const int colw = w * 16 + i * 4 + c4;
        const unsigned char* gp = Bbase + (size_t)((c + 1) * 64 + colw) * Cdim +
                                  32 * (gx ^ (colw & 7)) + godd * 16;
        unsigned char* lp = &sB[bf ^ 1][(w * 16 + i * 4) * 256];
        __builtin_amdgcn_global_load_lds(
            (const __attribute__((address_space(1))) void*)gp,
            (__attribute__((address_space(3))) void*)lp, 16, 0, 0);
      }
    }

    // Two 32-col slices per chunk; slice p's exp2 phase overlaps slice
    // p+1's reads/MFMAs.
    for (int p = 0; p < 2; ++p) {
      long bfr[2][8];
#pragma unroll
      for (int j = 0; j < 2; ++j)
#pragma unroll
        for (int s = 0; s < 8; ++s)
          bfr[j][s] = *reinterpret_cast<const long*>(
              &sB[bf][((p * 2 + j) * 16 + l15) * 256 +
                      (((s ^ sxor) << 4) + boff)]);

      f32x4 acc[2][2];
#pragma unroll
      for (int mi = 0; mi < 2; ++mi)
#pragma unroll
        for (int j = 0; j < 2; ++j) acc[mi][j] = (f32x4){0.f, 0.f, 0.f, 0.f};

      __builtin_amdgcn_s_setprio(1);
#pragma unroll
      for (int s = 0; s < 8; ++s)
#pragma unroll
        for (int mi = 0; mi < 2; ++mi)
#pragma unroll
          for (int j = 0; j < 2; ++j)
            acc[mi][j] = __builtin_amdgcn_mfma_f32_16x16x32_fp8_fp8(
                areg[s][mi], bfr[j][s], acc[mi][j], 0, 0, 0);
      __builtin_amdgcn_s_setprio(0);

      // rowexp += exp2(S_mfma)  (k2 pre-folded into A); pAll collects the
      // raw acc sum for the analytic positive term.
#pragma unroll
      for (int mi = 0; mi < 2; ++mi)
#pragma unroll
        for (int j = 0; j < 2; ++j)
#pragma unroll
          for (int r = 0; r < 4; ++r) {
            rowexp[mi * 4 + r] += __builtin_amdgcn_exp2f(acc[mi][j][r]);
            pAll += acc[mi][j][r];
          }
    }

    __syncthreads();  // buffer reuse; prefetch had full compute to land
  }

  // ---- epilogue: one reduce + atomic per row slot ----
#pragma unroll
  for (int idx = 0; idx < 8; ++idx) {
    float se = rowexp[idx];
    se += __shfl_xor(se, 1);
    se += __shfl_xor(se, 2);
    se += __shfl_xor(se, 4);
    se += __shfl_xor(se, 8);
    if (l15 == 0) {
      const int row =
          rg * 128 + w * 32 + (idx >> 2) * 16 + quad * 4 + (idx & 3);
      atomicAdd(&sumexp[row], se);
    }
  }

  // ---- positive-pair term: lane's cols are ≡ l15 (mod 8) ----
  float pl = ((l15 & 7) == bi) ? pAll : 0.f;
#pragma unroll
  for (int off = 1; off < 64; off <<= 1) pl += __shfl_xor(pl, off);
  if (lane == 0) atomicAdd(&Pacc[strip], pl);

  // ---- last block finalizes the loss ----
  __syncthreads();  // all waves' atomics issued before done-increment
  if (tid == 0) {
    __threadfence();
    is_last = (atomicAdd(done, 1u) == NBLK - 1) ? 1u : 0u;
  }
  __syncthreads();
  if (is_last) {
    __threadfence();  // acquire: all blocks' atomics visible
    float lsum = 0.f;
    for (int i = tid; i < Nvec; i += 256) lsum += logf(sumexp[i]);
#pragma unroll
    for (int off = 1; off < 64; off <<= 1) lsum += __shfl_xor(lsum, off);
    if ((tid & 63) == 0) part4[w] = lsum;
    __syncthreads();
    if (tid == 0) {
      float total_lse = 0.f;
#pragma unroll
      for (int i = 0; i < 4; ++i) total_lse += part4[i];
      float P = 0.f;
#pragma unroll
      for (int i = 0; i < 16; ++i) P += Pacc[i];
      // acc = k2*sim, ln2*k2 = 1/T -> P*ln2 = sum_pos sim/T
      P *= 0.69314718056f;  // ln 2
      out[0] = -(P - 1024.0f * total_lse) / (8388608.0f + 1e-8f);
    }
  }
}

extern "C" void kernel_launch(void* const* d_in, const int* in_sizes, int n_in,
                              void* d_out, int out_size, void* d_ws,
                              size_t ws_size, hipStream_t stream) {
  const float* rgb = (const float*)d_in[0];
  const float* x   = (const float*)d_in[1];
  char* ws = (char*)d_ws;
  unsigned char* rgbq = (unsigned char*)ws;                             // 2 MiB
  unsigned char* xq   = (unsigned char*)(ws + (size_t)2 * 1024 * 1024); // 2 MiB
  float* sumexp = (float*)(ws + (size_t)4 * 1024 * 1024);  // 8192 floats
  float* Pacc   = sumexp + Nvec;                           // 16 floats
  unsigned int* done = (unsigned int*)(Pacc + 16);

  // no memset dispatch: norm_kernel zeroes sumexp/Pacc/done (stream-ordered)
  norm_kernel<<<dim3(256, 2), 256, 0, stream>>>(rgb, x, rgbq, xq, sumexp,
                                                Pacc, done);
  gemm_loss_kernel<<<dim3(16, 64), 256, 0, stream>>>(rgbq, xq, sumexp, Pacc,
                                                     done, (float*)d_out);
}

// Round 4
// 131.017 us; speedup vs baseline: 1.6710x; 1.1758x over previous
//
#include <hip/hip_runtime.h>
#include <hip/hip_bf16.h>

// CrossModalContrastiveLoss: B=8, C=256, H=W=32 -> N=8192 vectors of dim 256.
// loss = -( P - 1024 * sum_i log(sum_j exp(S_ij)) ) / 8388608,
// S = normalize(rgb) @ normalize(x)^T / 0.1.
// positives for row i are cols j with j%8 == i/1024. A_q carries
// k2 = 10*log2(e) folded in at quantization, so S_mfma = k2*sim and
// exp(10*sim) = exp2(S_mfma).
//
// Round-13: R12's regression (55->94us) was an atomic-retirement convoy:
// 4096 same-line atomics to Pacc[16] (one 64B line, 256/word, 8-XCD
// ping-pong) + the new pre-done __syncthreads forcing every wave to drain
// vmcnt(0) -- i.e. wait for retirement of contended atomics -- before block
// end. MFMA busy time was unchanged (12.6 vs 12.9us); all +39us was stall.
// Fix: P reduced per-block in LDS -> ONE atomic per block to a UNIQUE
// address Pblk[bid] (no contention, fast retire), is_last sums 1024 floats.
// pAll split into pp[4] to break the serial add chain. Barrier kept (it
// fixes R10's latent visibility race).

#define HWsz 1024
#define Cdim 256
#define Nvec 8192
#define CHW  (Cdim * HWsz)
#define NBLK 1024   // 16 strips x 64 rowgroups

typedef __attribute__((ext_vector_type(4))) float f32x4;

// 32 vectors per block (all one batch), C split 8 ways. Quantizes to fp8
// e4m3 (rgb side pre-scaled by k2), stores (N,C) row-major. Also zeroes
// the accumulators the gemm kernel needs (replaces the memset dispatch).
__global__ __launch_bounds__(256) void norm_kernel(
    const float* __restrict__ rgb, const float* __restrict__ x,
    unsigned char* __restrict__ rgbq, unsigned char* __restrict__ xq,
    float* __restrict__ sumexp, float* __restrict__ Pblk,
    unsigned int* __restrict__ done) {
  __shared__ float ssp[8][32];
  __shared__ __align__(16) unsigned char tile[32][272];  // 272 = 16*17
  const int t = threadIdx.x;
  const int nl = t & 31;        // vector within block
  const int part = t >> 5;      // 0..7: channel chunk
  const int isx = blockIdx.y;
  const int bx = blockIdx.x;

  // ---- zero gemm accumulators (this kernel precedes gemm in-stream) ----
  if (t < 16) sumexp[(isx * 256 + bx) * 16 + t] = 0.f;
  if (t < 2)  Pblk[(isx * 256 + bx) * 2 + t] = 0.f;
  if (isx == 0 && bx == 0 && t == 63) *done = 0u;

  const float* src = isx ? x : rgb;
  unsigned char* dst = isx ? xq : rgbq;
  const int n0 = bx * 32;
  const int n = n0 + nl;
  const int b = n >> 10;        // uniform per block
  const int hw = n & 1023;
  const float* p = src + (size_t)b * CHW + (size_t)(part * 32) * HWsz + hw;

  float v[32];
  float ss = 0.f;
#pragma unroll
  for (int j = 0; j < 32; ++j) {
    v[j] = p[(size_t)j * HWsz];
    ss += v[j] * v[j];
  }
  ssp[part][nl] = ss;
  __syncthreads();
  float tot = 0.f;
#pragma unroll
  for (int q = 0; q < 8; ++q) tot += ssp[q][nl];
  const float k2 = 14.4269504089f;  // (1/T) * log2(e), folded into rgb side
  const float inv = (isx ? 1.0f : k2) / fmaxf(sqrtf(tot), 1e-12f);

#pragma unroll
  for (int c0 = 0; c0 < 32; c0 += 4) {
    int pk = 0;
    pk = __builtin_amdgcn_cvt_pk_fp8_f32(v[c0] * inv, v[c0 + 1] * inv, pk, false);
    pk = __builtin_amdgcn_cvt_pk_fp8_f32(v[c0 + 2] * inv, v[c0 + 3] * inv, pk, true);
    *reinterpret_cast<unsigned int*>(&tile[nl][part * 32 + c0]) =
        (unsigned int)pk;
  }
  __syncthreads();

  // coalesced store: 2 passes x (16 rows x 256 B)
#pragma unroll
  for (int pass = 0; pass < 2; ++pass) {
    const int r = pass * 16 + (t >> 4);
    const int ck = (t & 15) * 16;
    *reinterpret_cast<uint4*>(dst + (size_t)(n0 + r) * Cdim + ck) =
        *reinterpret_cast<const uint4*>(&tile[r][ck]);
  }
}

// Block = 4 waves, 128 rows x 512-col strip, fp8. A-panel 32 rows/wave in
// regs (8 s-steps x 2 mi longs = 32 VGPRs). B streamed as 8 chunks of 64
// cols x 256 K through double-buffered 2x16 KB LDS.
//
// fp8 LDS swizzle (16-B staging granule): col's 16 units placed at
//   phys(unit) = ((unit>>1) ^ (col&7) ^ ((unit&1)<<2)) + ((unit&1)<<3)
// Inverted on the GLOBAL address side so the wave-uniform base + lane*16
// constraint of global_load_lds is preserved.
__global__ __launch_bounds__(256, 4) void gemm_loss_kernel(
    const unsigned char* __restrict__ A, const unsigned char* __restrict__ Bq,
    float* __restrict__ sumexp, float* __restrict__ Pblk,
    unsigned int* __restrict__ done, float* __restrict__ out) {
  __shared__ __align__(16) unsigned char sB[2][16384];
  __shared__ float part4[4], part4b[4], pshare[4];
  __shared__ unsigned int is_last;

  const int tid  = threadIdx.x;
  const int lane = tid & 63;
  const int w    = tid >> 6;      // wave 0..3 -> rows w*32..+32
  const int strip = blockIdx.x;   // 0..15: cols strip*512..+512 (XCD-pinned)
  const int rg   = blockIdx.y;    // 0..63: rows rg*128..+128
  const int quad = lane >> 4;
  const int l15  = lane & 15;
  const int bi   = rg >> 3;       // batch of this rowgroup

  // ---- A fragments: direct global -> 32 regs/wave, once per block ----
  long areg[8][2];
#pragma unroll
  for (int mi = 0; mi < 2; ++mi) {
    const unsigned char* rp =
        A + (size_t)(rg * 128 + w * 32 + mi * 16 + l15) * Cdim + quad * 8;
#pragma unroll
    for (int s = 0; s < 8; ++s)
      areg[s][mi] = *reinterpret_cast<const long*>(rp + s * 32);
  }

  // staging lane constants: lane = c4*16 + u writes (col base+c4, slot u)
  const int u_  = l15;
  const int c4  = quad;
  const int gx  = (u_ & 7) ^ ((u_ >> 3) << 2);
  const int godd = u_ >> 3;   // global unit parity this slot holds
  // reader lane constants
  const int sxor = (l15 & 7) ^ ((quad >> 1) << 2);
  const int boff = ((quad >> 1) << 7) + ((quad & 1) << 3);

  float rowexp[8];
#pragma unroll
  for (int i = 0; i < 8; ++i) rowexp[i] = 0.f;
  float pp[4];   // 4 independent partial sums of raw acc (masked at end)
#pragma unroll
  for (int i = 0; i < 4; ++i) pp[i] = 0.f;

  const unsigned char* Bbase = Bq + (size_t)strip * 512 * Cdim;

  // prefetch chunk 0
#pragma unroll
  for (int i = 0; i < 4; ++i) {
    const int colw = w * 16 + i * 4 + c4;
    const unsigned char* gp = Bbase + (size_t)colw * Cdim +
                              32 * (gx ^ (colw & 7)) + godd * 16;
    unsigned char* lp = &sB[0][(w * 16 + i * 4) * 256];
    __builtin_amdgcn_global_load_lds(
        (const __attribute__((address_space(1))) void*)gp,
        (__attribute__((address_space(3))) void*)lp, 16, 0, 0);
  }
  __syncthreads();

  for (int c = 0; c < 8; ++c) {
    const int bf = c & 1;
    if (c < 7) {  // prefetch next chunk (overlaps this chunk's MFMA)
#pragma unroll
      for (int i = 0; i < 4; ++i) {
        const int colw = w * 16 + i * 4 + c4;
        const unsigned char* gp = Bbase + (size_t)((c + 1) * 64 + colw) * Cdim +
                                  32 * (gx ^ (colw & 7)) + godd * 16;
        unsigned char* lp = &sB[bf ^ 1][(w * 16 + i * 4) * 256];
        __builtin_amdgcn_global_load_lds(
            (const __attribute__((address_space(1))) void*)gp,
            (__attribute__((address_space(3))) void*)lp, 16, 0, 0);
      }
    }

    // Two 32-col slices per chunk; slice p's exp2 phase overlaps slice
    // p+1's reads/MFMAs.
    for (int p = 0; p < 2; ++p) {
      long bfr[2][8];
#pragma unroll
      for (int j = 0; j < 2; ++j)
#pragma unroll
        for (int s = 0; s < 8; ++s)
          bfr[j][s] = *reinterpret_cast<const long*>(
              &sB[bf][((p * 2 + j) * 16 + l15) * 256 +
                      (((s ^ sxor) << 4) + boff)]);

      f32x4 acc[2][2];
#pragma unroll
      for (int mi = 0; mi < 2; ++mi)
#pragma unroll
        for (int j = 0; j < 2; ++j) acc[mi][j] = (f32x4){0.f, 0.f, 0.f, 0.f};

      __builtin_amdgcn_s_setprio(1);
#pragma unroll
      for (int s = 0; s < 8; ++s)
#pragma unroll
        for (int mi = 0; mi < 2; ++mi)
#pragma unroll
          for (int j = 0; j < 2; ++j)
            acc[mi][j] = __builtin_amdgcn_mfma_f32_16x16x32_fp8_fp8(
                areg[s][mi], bfr[j][s], acc[mi][j], 0, 0, 0);
      __builtin_amdgcn_s_setprio(0);

      // rowexp += exp2(S_mfma)  (k2 pre-folded into A); pp[] collects the
      // raw acc sum for the analytic positive term (4 independent chains).
#pragma unroll
      for (int mi = 0; mi < 2; ++mi)
#pragma unroll
        for (int j = 0; j < 2; ++j)
#pragma unroll
          for (int r = 0; r < 4; ++r) {
            rowexp[mi * 4 + r] += __builtin_amdgcn_exp2f(acc[mi][j][r]);
            pp[r] += acc[mi][j][r];
          }
    }

    __syncthreads();  // buffer reuse; prefetch had full compute to land
  }

  // ---- epilogue: one reduce + atomic per row slot ----
#pragma unroll
  for (int idx = 0; idx < 8; ++idx) {
    float se = rowexp[idx];
    se += __shfl_xor(se, 1);
    se += __shfl_xor(se, 2);
    se += __shfl_xor(se, 4);
    se += __shfl_xor(se, 8);
    if (l15 == 0) {
      const int row =
          rg * 128 + w * 32 + (idx >> 2) * 16 + quad * 4 + (idx & 3);
      atomicAdd(&sumexp[row], se);
    }
  }

  // ---- positive-pair term: lane's cols are ≡ l15 (mod 8); per-block
  // LDS reduce -> ONE atomic to a block-private address (no contention) ----
  float pl = ((l15 & 7) == bi) ? (pp[0] + pp[1]) + (pp[2] + pp[3]) : 0.f;
#pragma unroll
  for (int off = 1; off < 64; off <<= 1) pl += __shfl_xor(pl, off);
  if (lane == 0) pshare[w] = pl;

  // barrier: publishes pshare AND drains all waves' sumexp atomics (fixes
  // the visibility race) -- retirement is cheap now (no same-line convoy).
  __syncthreads();
  if (tid == 0) {
    atomicAdd(&Pblk[rg * 16 + strip],
              (pshare[0] + pshare[1]) + (pshare[2] + pshare[3]));
    __threadfence();
    is_last = (atomicAdd(done, 1u) == NBLK - 1) ? 1u : 0u;
  }
  __syncthreads();

  // ---- last block finalizes the loss ----
  if (is_last) {
    __threadfence();  // acquire: all blocks' atomics visible
    float lsum = 0.f, pb = 0.f;
    for (int i = tid; i < Nvec; i += 256) lsum += logf(sumexp[i]);
#pragma unroll
    for (int i = 0; i < NBLK / 256; ++i) pb += Pblk[i * 256 + tid];
#pragma unroll
    for (int off = 1; off < 64; off <<= 1) {
      lsum += __shfl_xor(lsum, off);
      pb   += __shfl_xor(pb, off);
    }
    if ((tid & 63) == 0) { part4[w] = lsum; part4b[w] = pb; }
    __syncthreads();
    if (tid == 0) {
      float total_lse = 0.f, P = 0.f;
#pragma unroll
      for (int i = 0; i < 4; ++i) { total_lse += part4[i]; P += part4b[i]; }
      // acc = k2*sim, ln2*k2 = 1/T -> P*ln2 = sum_pos sim/T
      P *= 0.69314718056f;  // ln 2
      out[0] = -(P - 1024.0f * total_lse) / (8388608.0f + 1e-8f);
    }
  }
}

extern "C" void kernel_launch(void* const* d_in, const int* in_sizes, int n_in,
                              void* d_out, int out_size, void* d_ws,
                              size_t ws_size, hipStream_t stream) {
  const float* rgb = (const float*)d_in[0];
  const float* x   = (const float*)d_in[1];
  char* ws = (char*)d_ws;
  unsigned char* rgbq = (unsigned char*)ws;                             // 2 MiB
  unsigned char* xq   = (unsigned char*)(ws + (size_t)2 * 1024 * 1024); // 2 MiB
  float* sumexp = (float*)(ws + (size_t)4 * 1024 * 1024);  // 8192 floats
  float* Pblk   = sumexp + Nvec;                           // 1024 floats
  unsigned int* done = (unsigned int*)(Pblk + NBLK);

  // no memset dispatch: norm_kernel zeroes sumexp/Pblk/done (stream-ordered)
  norm_kernel<<<dim3(256, 2), 256, 0, stream>>>(rgb, x, rgbq, xq, sumexp,
                                                Pblk, done);
  gemm_loss_kernel<<<dim3(16, 64), 256, 0, stream>>>(rgbq, xq, sumexp, Pblk,
                                                     done, (float*)d_out);
}